// Round 1
// baseline (1234.432 us; speedup 1.0000x reference)
//
#include <hip/hip_runtime.h>

#define NN      10000
#define IN_DIM  128
#define E_DIM   32
#define NH      4
#define DH      32
#define HD      128   // NH*DH
#define NE_     640000
#define OUT_DIM 32

// ---------------------------------------------------------------------------
// Kernel 1: per node n (block of 128 threads, thread = output column j):
//   Q[n,j], K[n,j] to global; V[n,j] to LDS; then P[n,h,o] = V[n,h,:]@Wo_h[:,o]
// ---------------------------------------------------------------------------
__global__ __launch_bounds__(128) void qkvp_kernel(
    const float* __restrict__ x,
    const float* __restrict__ Wq, const float* __restrict__ bq,
    const float* __restrict__ Wk, const float* __restrict__ bk,
    const float* __restrict__ Wv, const float* __restrict__ bv,
    const float* __restrict__ Wo,
    float* __restrict__ Q, float* __restrict__ K, float* __restrict__ P)
{
    __shared__ float xs[IN_DIM];
    __shared__ float vs[HD];
    const int n = blockIdx.x;
    const int j = threadIdx.x;

    xs[j] = x[(size_t)n * IN_DIM + j];
    __syncthreads();

    float q = bq[j], k = bk[j], v = bv[j];
    #pragma unroll 8
    for (int i = 0; i < IN_DIM; ++i) {
        const float xv = xs[i];
        q = fmaf(xv, Wq[i * HD + j], q);
        k = fmaf(xv, Wk[i * HD + j], k);
        v = fmaf(xv, Wv[i * HD + j], v);
    }
    Q[(size_t)n * HD + j] = q;
    K[(size_t)n * HD + j] = k;
    vs[j] = v;
    __syncthreads();

    // P[n, h, o] with j = h*32 + o
    const int h = j >> 5, o = j & 31;
    float p = 0.f;
    #pragma unroll
    for (int d = 0; d < DH; ++d)
        p = fmaf(vs[h * DH + d], Wo[(h * DH + d) * OUT_DIM + o], p);
    P[(size_t)n * HD + j] = p;
}

// ---------------------------------------------------------------------------
// Kernel 2: one thread per edge.
//   ee[h]  = || edge_attr[e] @ We_h + be_h ||^2        (computed on the fly)
//   sc[h]  = (Q[src,h]·K[dst,h] + ee[h]) / sqrt(32)
//   alpha  = softmax over h
//   out[o] = sum_h alpha[h] * P[dst,h,o];  atomic into sums[src], cnt[src]++
// ---------------------------------------------------------------------------
__global__ __launch_bounds__(256) void edge_kernel(
    const int*   __restrict__ ei,
    const float* __restrict__ ea,
    const float* __restrict__ We, const float* __restrict__ be,
    const float* __restrict__ Q,  const float* __restrict__ K,
    const float* __restrict__ P,
    float* __restrict__ sums, float* __restrict__ cnt)
{
    const int e = blockIdx.x * blockDim.x + threadIdx.x;
    if (e >= NE_) return;

    const int src = ei[e];
    const int dst = ei[NE_ + e];

    // load edge_attr row (32 floats, 16B-aligned)
    float a[E_DIM];
    const float4* ea4 = reinterpret_cast<const float4*>(ea + (size_t)e * E_DIM);
    #pragma unroll
    for (int k4 = 0; k4 < E_DIM / 4; ++k4) {
        const float4 t = ea4[k4];
        a[k4 * 4 + 0] = t.x; a[k4 * 4 + 1] = t.y;
        a[k4 * 4 + 2] = t.z; a[k4 * 4 + 3] = t.w;
    }

    const float4* Qs = reinterpret_cast<const float4*>(Q + (size_t)src * HD);
    const float4* Kd = reinterpret_cast<const float4*>(K + (size_t)dst * HD);

    float sc[NH];
    #pragma unroll 1
    for (int h = 0; h < NH; ++h) {
        float ee = 0.f;
        #pragma unroll 1
        for (int d = 0; d < DH; ++d) {
            float ef = be[h * DH + d];
            #pragma unroll
            for (int k = 0; k < E_DIM; ++k)
                ef = fmaf(a[k], We[k * HD + h * DH + d], ef);
            ee = fmaf(ef, ef, ee);
        }
        float qk = 0.f;
        #pragma unroll
        for (int i = 0; i < HD / (4 * NH); ++i) {
            const float4 q4 = Qs[h * 8 + i];
            const float4 k4 = Kd[h * 8 + i];
            qk = fmaf(q4.x, k4.x, fmaf(q4.y, k4.y,
                 fmaf(q4.z, k4.z, fmaf(q4.w, k4.w, qk))));
        }
        sc[h] = (qk + ee) * 0.17677669529663687f;  // 1/sqrt(32)
    }

    // softmax over the 4 heads
    const float m = fmaxf(fmaxf(sc[0], sc[1]), fmaxf(sc[2], sc[3]));
    float alpha[NH], ssum = 0.f;
    #pragma unroll
    for (int h = 0; h < NH; ++h) { alpha[h] = __expf(sc[h] - m); ssum += alpha[h]; }
    const float inv = 1.f / ssum;
    #pragma unroll
    for (int h = 0; h < NH; ++h) alpha[h] *= inv;

    // out_e = sum_h alpha_h * P[dst,h,:]; scatter-add to src
    const float4* Pd = reinterpret_cast<const float4*>(P + (size_t)dst * HD);
    float* srow = sums + (size_t)src * OUT_DIM;
    #pragma unroll
    for (int i = 0; i < OUT_DIM / 4; ++i) {
        float4 acc = {0.f, 0.f, 0.f, 0.f};
        #pragma unroll
        for (int h = 0; h < NH; ++h) {
            const float4 p4 = Pd[h * 8 + i];
            acc.x = fmaf(alpha[h], p4.x, acc.x);
            acc.y = fmaf(alpha[h], p4.y, acc.y);
            acc.z = fmaf(alpha[h], p4.z, acc.z);
            acc.w = fmaf(alpha[h], p4.w, acc.w);
        }
        atomicAdd(&srow[i * 4 + 0], acc.x);
        atomicAdd(&srow[i * 4 + 1], acc.y);
        atomicAdd(&srow[i * 4 + 2], acc.z);
        atomicAdd(&srow[i * 4 + 3], acc.w);
    }
    atomicAdd(&cnt[src], 1.0f);
}

// ---------------------------------------------------------------------------
// Kernel 3: out[n,o] = cnt[n] > 0 ? sums[n,o]/cnt[n] + bo[o] : 0
// ---------------------------------------------------------------------------
__global__ __launch_bounds__(256) void final_kernel(
    const float* __restrict__ sums, const float* __restrict__ cnt,
    const float* __restrict__ bo, float* __restrict__ out)
{
    const int i = blockIdx.x * blockDim.x + threadIdx.x;
    if (i >= NN * OUT_DIM) return;
    const int n = i / OUT_DIM, o = i % OUT_DIM;
    const float c = cnt[n];
    out[i] = (c > 0.f) ? (sums[i] / c + bo[o]) : 0.f;
}

extern "C" void kernel_launch(void* const* d_in, const int* in_sizes, int n_in,
                              void* d_out, int out_size, void* d_ws, size_t ws_size,
                              hipStream_t stream)
{
    const float* x   = (const float*)d_in[0];
    const int*   ei  = (const int*)  d_in[1];
    const float* ea  = (const float*)d_in[2];
    const float* Wq  = (const float*)d_in[3];
    const float* bq  = (const float*)d_in[4];
    const float* Wk  = (const float*)d_in[5];
    const float* bk  = (const float*)d_in[6];
    const float* Wv  = (const float*)d_in[7];
    const float* bv  = (const float*)d_in[8];
    const float* We  = (const float*)d_in[9];
    const float* be  = (const float*)d_in[10];
    const float* Wo  = (const float*)d_in[11];
    const float* bo  = (const float*)d_in[12];
    float* out = (float*)d_out;

    // workspace layout (floats): Q[NN*HD] K[NN*HD] P[NN*HD] sums[NN*OUT] cnt[NN]
    float* Q    = (float*)d_ws;
    float* K    = Q + (size_t)NN * HD;
    float* P    = K + (size_t)NN * HD;
    float* sums = P + (size_t)NN * HD;
    float* cnt  = sums + (size_t)NN * OUT_DIM;

    // zero the accumulators (sums + cnt are contiguous)
    hipMemsetAsync(sums, 0, ((size_t)NN * OUT_DIM + NN) * sizeof(float), stream);

    qkvp_kernel<<<NN, 128, 0, stream>>>(x, Wq, bq, Wk, bk, Wv, bv, Wo, Q, K, P);

    edge_kernel<<<(NE_ + 255) / 256, 256, 0, stream>>>(ei, ea, We, be, Q, K, P, sums, cnt);

    final_kernel<<<(NN * OUT_DIM + 255) / 256, 256, 0, stream>>>(sums, cnt, bo, out);
}

// Round 2
// 306.982 us; speedup vs baseline: 4.0212x; 4.0212x over previous
//
#include <hip/hip_runtime.h>

#define NN      10000
#define IN_DIM  128
#define E_DIM   32
#define NH      4
#define DH      32
#define HD      128   // NH*DH
#define NE_     640000
#define OUT_DIM 32
#define SCAN_T  1024
#define CHUNK   10    // SCAN_T*CHUNK >= NN

// ---------------------------------------------------------------------------
// Kernel 1: per node n (block of 128 threads, thread = output column j):
//   Q[n,j], K[n,j] to global; V[n,j] to LDS; then P[n,h,o] = V[n,h,:]@Wo_h[:,o]
// ---------------------------------------------------------------------------
__global__ __launch_bounds__(128) void qkvp_kernel(
    const float* __restrict__ x,
    const float* __restrict__ Wq, const float* __restrict__ bq,
    const float* __restrict__ Wk, const float* __restrict__ bk,
    const float* __restrict__ Wv, const float* __restrict__ bv,
    const float* __restrict__ Wo,
    float* __restrict__ Q, float* __restrict__ K, float* __restrict__ P)
{
    __shared__ float xs[IN_DIM];
    __shared__ float vs[HD];
    const int n = blockIdx.x;
    const int j = threadIdx.x;

    xs[j] = x[(size_t)n * IN_DIM + j];
    __syncthreads();

    float q = bq[j], k = bk[j], v = bv[j];
    #pragma unroll 8
    for (int i = 0; i < IN_DIM; ++i) {
        const float xv = xs[i];
        q = fmaf(xv, Wq[i * HD + j], q);
        k = fmaf(xv, Wk[i * HD + j], k);
        v = fmaf(xv, Wv[i * HD + j], v);
    }
    Q[(size_t)n * HD + j] = q;
    K[(size_t)n * HD + j] = k;
    vs[j] = v;
    __syncthreads();

    const int h = j >> 5, o = j & 31;
    float p = 0.f;
    #pragma unroll
    for (int d = 0; d < DH; ++d)
        p = fmaf(vs[h * DH + d], Wo[(h * DH + d) * OUT_DIM + o], p);
    P[(size_t)n * HD + j] = p;
}

// ---------------------------------------------------------------------------
// Kernel 1b: WeT[j][k] = We[k][j]   (128 x 32 <- 32 x 128), contiguous k rows
// ---------------------------------------------------------------------------
__global__ __launch_bounds__(1024) void wet_kernel(
    const float* __restrict__ We, float* __restrict__ WeT)
{
    const int i = blockIdx.x * 1024 + threadIdx.x;   // i = j*32 + k
    if (i >= HD * E_DIM) return;
    const int j = i >> 5, k = i & 31;
    WeT[i] = We[k * HD + j];
}

// ---------------------------------------------------------------------------
// Kernel 2: degree histogram over src
// ---------------------------------------------------------------------------
__global__ __launch_bounds__(256) void hist_kernel(
    const int* __restrict__ ei, int* __restrict__ deg)
{
    const int e = blockIdx.x * blockDim.x + threadIdx.x;
    if (e >= NE_) return;
    atomicAdd(&deg[ei[e]], 1);
}

// ---------------------------------------------------------------------------
// Kernel 3: single-block exclusive scan of deg -> off, cur
// ---------------------------------------------------------------------------
__global__ __launch_bounds__(SCAN_T) void scan_kernel(
    const int* __restrict__ deg, int* __restrict__ off, int* __restrict__ cur)
{
    __shared__ int s[SCAN_T];
    const int t = threadIdx.x;
    const int base = t * CHUNK;
    int v[CHUNK];
    int sum = 0;
    #pragma unroll
    for (int i = 0; i < CHUNK; ++i) {
        const int idx = base + i;
        v[i] = (idx < NN) ? deg[idx] : 0;
        sum += v[i];
    }
    s[t] = sum;
    __syncthreads();
    for (int d = 1; d < SCAN_T; d <<= 1) {
        const int val = (t >= d) ? s[t - d] : 0;
        __syncthreads();
        s[t] += val;
        __syncthreads();
    }
    int run = s[t] - sum;   // exclusive prefix
    #pragma unroll
    for (int i = 0; i < CHUNK; ++i) {
        const int idx = base + i;
        if (idx < NN) { off[idx] = run; cur[idx] = run; run += v[i]; }
    }
}

// ---------------------------------------------------------------------------
// Kernel 4: one thread per edge: scores -> alpha; slot = atomicAdd(cur[src]);
//           write (dst, alpha4) payload into slot.
// ---------------------------------------------------------------------------
__global__ __launch_bounds__(256) void score_kernel(
    const int*   __restrict__ ei,
    const float* __restrict__ ea,
    const float* __restrict__ WeT, const float* __restrict__ be,
    const float* __restrict__ Q,  const float* __restrict__ K,
    int* __restrict__ cur, int* __restrict__ pdst, float4* __restrict__ palpha)
{
    const int e = blockIdx.x * blockDim.x + threadIdx.x;
    if (e >= NE_) return;

    const int src = ei[e];
    const int dst = ei[NE_ + e];

    // edge_attr row -> registers
    float a[E_DIM];
    const float4* ea4 = reinterpret_cast<const float4*>(ea + (size_t)e * E_DIM);
    #pragma unroll
    for (int k4 = 0; k4 < E_DIM / 4; ++k4) {
        const float4 t = ea4[k4];
        a[k4 * 4 + 0] = t.x; a[k4 * 4 + 1] = t.y;
        a[k4 * 4 + 2] = t.z; a[k4 * 4 + 3] = t.w;
    }

    const float4* Qs = reinterpret_cast<const float4*>(Q + (size_t)src * HD);
    const float4* Kd = reinterpret_cast<const float4*>(K + (size_t)dst * HD);

    float sc[NH];
    #pragma unroll 1
    for (int h = 0; h < NH; ++h) {
        float ee = 0.f;
        #pragma unroll 2
        for (int d = 0; d < DH; ++d) {
            const int j = h * DH + d;
            const float* __restrict__ wrow = WeT + j * E_DIM;  // lane-uniform
            float ef = be[j];
            #pragma unroll
            for (int k = 0; k < E_DIM; ++k)
                ef = fmaf(a[k], wrow[k], ef);
            ee = fmaf(ef, ef, ee);
        }
        float qk = 0.f;
        #pragma unroll
        for (int i = 0; i < DH / 4; ++i) {
            const float4 q4 = Qs[h * 8 + i];
            const float4 k4 = Kd[h * 8 + i];
            qk = fmaf(q4.x, k4.x, fmaf(q4.y, k4.y,
                 fmaf(q4.z, k4.z, fmaf(q4.w, k4.w, qk))));
        }
        sc[h] = (qk + ee) * 0.17677669529663687f;  // 1/sqrt(32)
    }

    const float m = fmaxf(fmaxf(sc[0], sc[1]), fmaxf(sc[2], sc[3]));
    float al[NH], ssum = 0.f;
    #pragma unroll
    for (int h = 0; h < NH; ++h) { al[h] = __expf(sc[h] - m); ssum += al[h]; }
    const float inv = 1.f / ssum;

    const int pos = atomicAdd(&cur[src], 1);
    pdst[pos] = dst;
    palpha[pos] = make_float4(al[0] * inv, al[1] * inv, al[2] * inv, al[3] * inv);
}

// ---------------------------------------------------------------------------
// Kernel 5: per node (1 wave): out[n,o] = (1/deg) * sum_seg sum_h al_h P[dst,h,o] + bo
// ---------------------------------------------------------------------------
__global__ __launch_bounds__(64) void gather_kernel(
    const int* __restrict__ off, const int* __restrict__ deg,
    const int* __restrict__ pdst, const float4* __restrict__ palpha,
    const float* __restrict__ P, const float* __restrict__ bo,
    float* __restrict__ out)
{
    const int n = blockIdx.x;
    const int d = deg[n];
    const int start = off[n];
    const int lane = threadIdx.x;
    const int o = lane & 31, r = lane >> 5;

    float acc = 0.f;
    for (int i = r; i < d; i += 2) {
        const int e = start + i;
        const int dst = pdst[e];
        const float4 al = palpha[e];
        const float* __restrict__ Pr = P + (size_t)dst * HD;
        acc += al.x * Pr[o] + al.y * Pr[DH + o]
             + al.z * Pr[2 * DH + o] + al.w * Pr[3 * DH + o];
    }
    acc += __shfl_xor(acc, 32, 64);
    if (lane < 32)
        out[(size_t)n * OUT_DIM + o] = (d > 0) ? (acc / (float)d + bo[o]) : 0.f;
}

extern "C" void kernel_launch(void* const* d_in, const int* in_sizes, int n_in,
                              void* d_out, int out_size, void* d_ws, size_t ws_size,
                              hipStream_t stream)
{
    const float* x   = (const float*)d_in[0];
    const int*   ei  = (const int*)  d_in[1];
    const float* ea  = (const float*)d_in[2];
    const float* Wq  = (const float*)d_in[3];
    const float* bq  = (const float*)d_in[4];
    const float* Wk  = (const float*)d_in[5];
    const float* bk  = (const float*)d_in[6];
    const float* Wv  = (const float*)d_in[7];
    const float* bv  = (const float*)d_in[8];
    const float* We  = (const float*)d_in[9];
    const float* be  = (const float*)d_in[10];
    const float* Wo  = (const float*)d_in[11];
    const float* bo  = (const float*)d_in[12];
    float* out = (float*)d_out;

    // workspace layout (16B-aligned chunks)
    float* Q      = (float*)d_ws;                       // NN*HD
    float* K      = Q + (size_t)NN * HD;                // NN*HD
    float* P      = K + (size_t)NN * HD;                // NN*HD
    float* WeT    = P + (size_t)NN * HD;                // HD*E_DIM = 4096
    float4* palpha= (float4*)(WeT + HD * E_DIM);        // NE_ float4
    int*   pdst   = (int*)(palpha + NE_);               // NE_
    int*   deg    = pdst + NE_;                         // NN
    int*   off    = deg + NN;                           // NN
    int*   cur    = off + NN;                           // NN

    hipMemsetAsync(deg, 0, NN * sizeof(int), stream);

    qkvp_kernel<<<NN, 128, 0, stream>>>(x, Wq, bq, Wk, bk, Wv, bv, Wo, Q, K, P);
    wet_kernel<<<(HD * E_DIM + 1023) / 1024, 1024, 0, stream>>>(We, WeT);
    hist_kernel<<<(NE_ + 255) / 256, 256, 0, stream>>>(ei, deg);
    scan_kernel<<<1, SCAN_T, 0, stream>>>(deg, off, cur);
    score_kernel<<<(NE_ + 255) / 256, 256, 0, stream>>>(ei, ea, WeT, be, Q, K,
                                                        cur, pdst, palpha);
    gather_kernel<<<NN, 64, 0, stream>>>(off, deg, pdst, palpha, P, bo, out);
}